// Round 3
// baseline (725.788 us; speedup 1.0000x reference)
//
#include <hip/hip_runtime.h>
#include <stdint.h>

typedef __attribute__((ext_vector_type(8))) __bf16 bf16x8;
typedef __attribute__((ext_vector_type(16))) float f32x16;

constexpr int CIN = 256, COUT = 256, HH = 512, WW = 512;
constexpr int BC = 16;           // input channels per K-iteration
constexpr int NCB = CIN / BC;    // 16 channel blocks
constexpr int MT = 128;          // out-channels per workgroup
constexpr int TY = 12, TX = 32;  // pixel tile: 12 rows x 32 cols
constexpr int XROWS = TY + 2;    // 14 staged input rows

__device__ __forceinline__ unsigned short f2bf(float f) {
    union { float f; unsigned int u; } v; v.f = f;
    return (unsigned short)((v.u + 0x7fffu + ((v.u >> 16) & 1u)) >> 16);  // RNE
}

// 16B zero source for OOB staging loads (device .bss -> zero, never written)
__device__ __align__(256) unsigned short g_zero16[16] = {};

// async global->LDS, 16B per lane; LDS dest = wave-uniform base + lane*16
__device__ __forceinline__ void gload16(const void* g, const void* l) {
    __builtin_amdgcn_global_load_lds(
        (const __attribute__((address_space(1))) unsigned int*)g,
        (__attribute__((address_space(3))) unsigned int*)l, 16, 0, 0);
}

// ---------------- weight transform: wt2[cb][tap][k][ci] bf16 ----------------
__global__ void wt_transform2(const float* __restrict__ w, unsigned short* __restrict__ wt2) {
    const int cbtap = blockIdx.x;              // [0, 144)
    const int cb = cbtap / 9, tap = cbtap - cb * 9;
    #pragma unroll 4
    for (int e = threadIdx.x; e < 4096; e += 256) {
        const int k = e >> 4, ci = e & 15;
        wt2[cbtap * 4096 + e] = f2bf(w[(k * CIN + cb * BC + ci) * 9 + tap]);
    }
}

// ---------------- input transform: xb[cb][y][x][ci] bf16 ----------------
__global__ __launch_bounds__(256)
void x_transform(const float* __restrict__ x, unsigned short* __restrict__ xb) {
    __shared__ __align__(16) float Xl[16][72];
    const int b   = blockIdx.x;               // 16384 = 512y * 8xc * 4cbg
    const int y   = b >> 5;
    const int xc  = (b >> 2) & 7;
    const int cbg = b & 3;
    const int x0  = xc * 64;
    const int tid = threadIdx.x;
    const int ci  = tid >> 4, p4 = (tid & 15) << 2;   // load mapping
    const int px  = tid >> 2, cig = tid & 3;          // store mapping
    #pragma unroll 1
    for (int g = 0; g < 4; ++g) {
        const int cb = cbg * 4 + g;
        const float4 v = *reinterpret_cast<const float4*>(
            x + ((long long)(cb * 16 + ci) * HH + y) * WW + x0 + p4);
        *reinterpret_cast<float4*>(&Xl[ci][p4]) = v;
        __syncthreads();
        ushort4 o;
        o.x = f2bf(Xl[cig * 4 + 0][px]);
        o.y = f2bf(Xl[cig * 4 + 1][px]);
        o.z = f2bf(Xl[cig * 4 + 2][px]);
        o.w = f2bf(Xl[cig * 4 + 3][px]);
        *reinterpret_cast<ushort4*>(
            xb + (((long long)cb * HH + y) * WW + x0 + px) * 16 + cig * 4) = o;
        __syncthreads();
    }
}

// ---------------- main conv kernel: 2-phase pipelined, N=6 ----------------
__global__ __launch_bounds__(256, 1)
void conv_mfma4(const unsigned short* __restrict__ xb, const unsigned short* __restrict__ wt2,
                float* __restrict__ out) {
    __shared__ __align__(16) unsigned short Wl[2][9][MT][16];      // 73728 B
    __shared__ __align__(16) unsigned short Xs[2][XROWS][36][16];  // 32256 B (total 105984)

    const int bid = blockIdx.x;
    // bijective XCD swizzle (1376 = 8*172); consecutive swz pairs (same tile,
    // two k0 halves) come from bids b,b+8 -> same XCD -> shared X slab L2-local.
    const int swz = (bid & 7) * 172 + (bid >> 3);
    const int k0 = (swz & 1) * MT;
    const int tile = swz >> 1;                 // 688 tiles = 16x * 43y
    const int x0 = (tile & 15) * TX;
    const int y0 = (tile >> 4) * TY;           // last y-tile (y0=504) partially OOB

    const int tid = threadIdx.x;
    const int lane = tid & 63;
    const int wave = tid >> 6;
    const int wm = wave & 1;                   // m-half (64 out-channels)
    const int wn = wave >> 1;                  // n-half (6 pixel rows)
    const int ln31 = lane & 31;
    const int lh8 = (lane >> 5) * 8;

    f32x16 acc[2][6];
    #pragma unroll
    for (int i = 0; i < 2; ++i)
        #pragma unroll
        for (int j = 0; j < 6; ++j)
            #pragma unroll
            for (int r = 0; r < 16; ++r) acc[i][j][r] = 0.f;

    const unsigned short* wsrc0 = wt2 + (size_t)k0 * 16 + (size_t)tid * 8;

    auto STAGE = [&](int cbn, int bufn) {
        // W panel: wave stages its 32-row quarter for all 9 taps (9 x 1KB)
        const unsigned short* ws = wsrc0 + (size_t)cbn * 9 * 4096;
        unsigned short* wld = &Wl[bufn][0][0][0] + wave * 512;
        #pragma unroll
        for (int i = 0; i < 9; ++i)
            gload16(ws + (size_t)i * 4096, wld + i * 2048);
        // X slab: 14 rows x (main 32px + 2px halo) = 28 slots, 7 per wave
        #pragma unroll
        for (int k = 0; k < 7; ++k) {
            const int slot = wave * 7 + k;
            const int row = slot >> 1, part = slot & 1;
            const int yy = y0 - 1 + row;
            const bool rok = (unsigned)yy < (unsigned)HH;
            const size_t rowb = ((size_t)cbn * HH + (rok ? yy : 0)) * WW;
            if (part == 0) {
                const int gx = x0 - 1 + (lane >> 1);
                const bool ok = rok && ((unsigned)gx < (unsigned)WW);
                const unsigned short* gs = ok ? xb + (rowb + gx) * 16 + (lane & 1) * 8 : g_zero16;
                gload16(gs, &Xs[bufn][row][0][0]);
            } else if (lane < 4) {
                const int gx2 = x0 + 31 + (lane >> 1);
                const bool ok2 = rok && gx2 < WW;
                const unsigned short* gs2 = ok2 ? xb + (rowb + gx2) * 16 + (lane & 1) * 8 : g_zero16;
                gload16(gs2, &Xs[bufn][row][32][0]);
            }
        }
    };

    // prologue: stage cb=0, drain, sync
    STAGE(0, 0);
    asm volatile("s_waitcnt vmcnt(0)" ::: "memory");
    __builtin_amdgcn_s_barrier();

    #pragma unroll 2
    for (int cb = 0; cb < NCB; ++cb) {
        const int cur = cb & 1;
        // issue next tile's staging FIRST; its latency hides under this MFMA phase
        if (cb + 1 < NCB) STAGE(cb + 1, cur ^ 1);

        // MFMA phase: 3 s-cols x (8 cached B-rows, 3 taps x 2x6 outer product)
        #pragma unroll
        for (int s = 0; s < 3; ++s) {
            bf16x8 b[8];
            #pragma unroll
            for (int o = 0; o < 8; ++o)
                b[o] = *reinterpret_cast<const bf16x8*>(&Xs[cur][wn * 6 + o][s + ln31][lh8]);
            #pragma unroll
            for (int rr = 0; rr < 3; ++rr) {
                const int tap = rr * 3 + s;
                const bf16x8 a0 = *reinterpret_cast<const bf16x8*>(&Wl[cur][tap][wm * 64 + ln31][lh8]);
                const bf16x8 a1 = *reinterpret_cast<const bf16x8*>(&Wl[cur][tap][wm * 64 + 32 + ln31][lh8]);
                #pragma unroll
                for (int j = 0; j < 6; ++j) {
                    acc[0][j] = __builtin_amdgcn_mfma_f32_32x32x16_bf16(a0, b[j + rr], acc[0][j], 0, 0, 0);
                    acc[1][j] = __builtin_amdgcn_mfma_f32_32x32x16_bf16(a1, b[j + rr], acc[1][j], 0, 0, 0);
                }
            }
        }

        // next stage complete (issued ~3456 cyc ago) + all waves done reading cur
        asm volatile("s_waitcnt vmcnt(0)" ::: "memory");
        __builtin_amdgcn_s_barrier();
    }

    // ---- epilogue: C/D map col=lane&31, row=(reg&3)+8*(reg>>2)+4*(lane>>5)
    #pragma unroll
    for (int i = 0; i < 2; ++i) {
        const int mb = k0 + wm * 64 + i * 32 + (lane >> 5) * 4;
        #pragma unroll
        for (int j = 0; j < 6; ++j) {
            const int py = y0 + wn * 6 + j;
            if (py < HH) {
                const long long px = x0 + ln31;
                #pragma unroll
                for (int r = 0; r < 16; ++r) {
                    const int m = mb + (r & 3) + 8 * (r >> 2);
                    out[((long long)m * HH + py) * WW + px] = acc[i][j][r];
                }
            }
        }
    }
}

// ---------------- safety fallback (ws too small) ----------------
__global__ void conv_naive(const float* __restrict__ x, const float* __restrict__ w,
                           float* __restrict__ out) {
    const int k = blockIdx.x;
    const int y = blockIdx.y;
    const int xx = blockIdx.z * 256 + threadIdx.x;
    float a = 0.f;
    for (int c = 0; c < CIN; ++c) {
        const float* wp = w + ((k * CIN + c) * 9);
        const float* xp = x + (long long)c * HH * WW;
        #pragma unroll
        for (int r = 0; r < 3; ++r) {
            const int yy = y + r - 1;
            if ((unsigned)yy >= (unsigned)HH) continue;
            const float* row = xp + (long long)yy * WW;
            #pragma unroll
            for (int s = 0; s < 3; ++s) {
                const int gx = xx + s - 1;
                const float v = ((unsigned)gx < (unsigned)WW) ? row[gx] : 0.f;
                a += wp[r * 3 + s] * v;
            }
        }
    }
    out[((long long)k * HH + y) * WW + xx] = a;
}

extern "C" void kernel_launch(void* const* d_in, const int* in_sizes, int n_in,
                              void* d_out, int out_size, void* d_ws, size_t ws_size,
                              hipStream_t stream) {
    const float* x = (const float*)d_in[0];
    const float* w = (const float*)d_in[1];
    float* out = (float*)d_out;

    const size_t xb_bytes  = (size_t)NCB * HH * WW * BC * sizeof(unsigned short);  // 128 MiB
    const size_t wt2_bytes = (size_t)144 * 4096 * sizeof(unsigned short);          // 1.125 MiB

    if (ws_size >= xb_bytes + wt2_bytes) {
        unsigned short* xb  = (unsigned short*)d_ws;
        unsigned short* wt2 = (unsigned short*)d_ws + xb_bytes / sizeof(unsigned short);
        x_transform<<<16384, 256, 0, stream>>>(x, xb);      // rebuild every call (ws re-poisoned)
        wt_transform2<<<144, 256, 0, stream>>>(w, wt2);
        conv_mfma4<<<1376, 256, 0, stream>>>(xb, wt2, out); // 43y * 16x * 2k0
    } else {
        conv_naive<<<dim3(256, 512, 2), 256, 0, stream>>>(x, w, out);
    }
}